// Round 11
// baseline (377.265 us; speedup 1.0000x reference)
//
#include <hip/hip_runtime.h>
#include <math.h>
#include <stdint.h>

#define Bn 2
#define Ln 2048
#define Dn 1024
#define Hn 16
#define DHn 64
#define Un 1228
#define BHn (Bn*Hn)
#define SCALE 0.125f
// refine window: exact re-rank of WIN rows around the top-k cut (hi+lo ~22-bit)
#define WIN 32
#define WHALF 16
// pre-split power-of-2 scales (dodge fp16 subnormal flush on lo terms)
#define SXf 16.0f     // x
#define SWf 256.0f    // all W
#define SQf 16.0f     // Q, K
#define SVf 16.0f     // V
#define SPf 16.0f     // softmax P
#define ESC_PROJ (1.0f / 4096.0f)    // 1/(SX*SW)
#define ESC_OUT  (1.0f / 65536.0f)   // 1/(SPf*SVf*SWf)
#define PSC (SCALE / 256.0f)         // score unscale: 1/(SQ*SQ) * SCALE
#define QPS 88                        // P/Q LDS stride (176B: 2-way banks)

typedef _Float16 f16;
typedef __attribute__((ext_vector_type(8))) _Float16 f16x8;
typedef __attribute__((ext_vector_type(4))) float f32x4;
struct h4s { f16 x, y, z, w; };

__device__ __forceinline__ void splitf16(float f, f16& hi, f16& lo) {
  hi = (f16)f;                 // RTNE
  lo = (f16)(f - (float)hi);   // residual, ~22 mantissa bits total
}

// async global->LDS, 16B per lane (wave-uniform base + lane*16)
__device__ __forceinline__ void gl_lds16(const void* g, void* l) {
  __builtin_amdgcn_global_load_lds(
      (const __attribute__((address_space(1))) void*)g,
      (__attribute__((address_space(3))) void*)l, 16, 0, 0);
}

#define MFMA(a, b, c) __builtin_amdgcn_mfma_f32_16x16x32_f16((a), (b), (c), 0, 0, 0)

// ------- fused prep: blocks 0-4095 split x; 4096-5119 transpose+split W0..W3 -------
__global__ __launch_bounds__(256) void prep_fused(
    const float* __restrict__ x, f16* __restrict__ xh, f16* __restrict__ xl, int n4,
    const float* __restrict__ W0, const float* __restrict__ W1,
    const float* __restrict__ W2, const float* __restrict__ W3,
    f16* __restrict__ oh, f16* __restrict__ ol) {
  __shared__ float ts[64][65];
  const int t = threadIdx.x;
  const int bid = blockIdx.x;
  if (bid < 4096) {
    int i = bid * 256 + t;
    if (i >= n4) return;
    float4 v = ((const float4*)x)[i];
    h4s h, l;
    splitf16(v.x * SXf, h.x, l.x); splitf16(v.y * SXf, h.y, l.y);
    splitf16(v.z * SXf, h.z, l.z); splitf16(v.w * SXf, h.w, l.w);
    ((h4s*)xh)[i] = h; ((h4s*)xl)[i] = l;
    return;
  }
  const int r = bid - 4096;                 // 0..1023
  const int r0 = (r & 15) * 64, c0 = ((r >> 4) & 15) * 64, z = r >> 8;
  const float* in = (z == 0) ? W0 : (z == 1) ? W1 : (z == 2) ? W2 : W3;
#pragma unroll
  for (int c = 0; c < 4; ++c) {
    int f = (c * 256 + t) * 4; int row = f >> 6, col = f & 63;
    float4 v = *(const float4*)&in[(size_t)(r0 + row) * Dn + c0 + col];
    ts[row][col] = v.x; ts[row][col + 1] = v.y; ts[row][col + 2] = v.z; ts[row][col + 3] = v.w;
  }
  __syncthreads();
#pragma unroll
  for (int c = 0; c < 4; ++c) {
    int f = (c * 256 + t) * 4; int crow = f >> 6, rcol = f & 63;
    h4s h, l;
    splitf16(ts[rcol + 0][crow] * SWf, h.x, l.x);
    splitf16(ts[rcol + 1][crow] * SWf, h.y, l.y);
    splitf16(ts[rcol + 2][crow] * SWf, h.z, l.z);
    splitf16(ts[rcol + 3][crow] * SWf, h.w, l.w);
    size_t o = (size_t)(z * 1024 + c0 + crow) * Dn + r0 + rcol;
    *(h4s*)&oh[o] = h; *(h4s*)&ol[o] = l;
  }
}

// ------- fused QKV GEMM (2-phase, proven r8 form): [4096 x 3072] -------
// Single-buffer: implicit wave-level overlap at ~25% occupancy already hides the
// staging latency (m114); explicit dbuf costs occupancy and regressed (r9).
// Epilogue: Q/K hi/lo f16 pairs; V f16.
__global__ void gemm_qkv(
    const f16* __restrict__ Ah, const f16* __restrict__ Al,
    const f16* __restrict__ Bth, const f16* __restrict__ Btl,
    const float* __restrict__ bq, const float* __restrict__ bk, const float* __restrict__ bv,
    f16* __restrict__ Qbh, f16* __restrict__ Qbl,
    f16* __restrict__ Kbh, f16* __restrict__ Kbl,
    f16* __restrict__ Vh16, int K) {
  __shared__ f16 sAh[128 * 32], sAl[128 * 32], sBh[128 * 32], sBl[128 * 32];
  const int t = threadIdx.x;
  const int w = t >> 6, lane = t & 63, lm = lane & 15, q = lane >> 4;
  const int wr = w >> 1, wc = w & 1;
  const int n0 = blockIdx.x * 128, m0 = blockIdx.y * 128;
  f32x4 acc[4][4] = {};
  for (int k0 = 0; k0 < K; k0 += 32) {
    const f16* s0 = Ah + (size_t)m0 * K + k0;
    const f16* s1 = Al + (size_t)m0 * K + k0;
    const f16* s2 = Bth + (size_t)n0 * K + k0;
    const f16* s3 = Btl + (size_t)n0 * K + k0;
#pragma unroll
    for (int c = 0; c < 2; ++c) {
      int f = (c * 256 + t) * 8; int row = f >> 5, col = f & 31;
      size_t go = (size_t)row * K + col;
      gl_lds16(s0 + go, &sAh[f]);
      gl_lds16(s1 + go, &sAl[f]);
      gl_lds16(s2 + go, &sBh[f]);
      gl_lds16(s3 + go, &sBl[f]);
    }
    __syncthreads();
    f16x8 a_h[4], a_l[4], b_h[4], b_l[4];
#pragma unroll
    for (int mi = 0; mi < 4; ++mi) {
      int r = (wr * 64 + mi * 16 + lm) * 32 + q * 8;
      a_h[mi] = *(const f16x8*)&sAh[r];
      a_l[mi] = *(const f16x8*)&sAl[r];
    }
#pragma unroll
    for (int ni = 0; ni < 4; ++ni) {
      int r = (wc * 64 + ni * 16 + lm) * 32 + q * 8;
      b_h[ni] = *(const f16x8*)&sBh[r];
      b_l[ni] = *(const f16x8*)&sBl[r];
    }
#pragma unroll
    for (int mi = 0; mi < 4; ++mi)
#pragma unroll
      for (int ni = 0; ni < 4; ++ni) {
        acc[mi][ni] = MFMA(a_h[mi], b_h[ni], acc[mi][ni]);
        acc[mi][ni] = MFMA(a_h[mi], b_l[ni], acc[mi][ni]);
        acc[mi][ni] = MFMA(a_l[mi], b_h[ni], acc[mi][ni]);
      }
    __syncthreads();
  }
#pragma unroll
  for (int mi = 0; mi < 4; ++mi)
#pragma unroll
    for (int ni = 0; ni < 4; ++ni) {
      int nglob = n0 + wc * 64 + ni * 16;         // 16-aligned, wave-uniform segment
      int seg = nglob >> 10;
      int c = (nglob & 1023) + lm;                // column within segment
      const float* bp = (seg == 0) ? bq : (seg == 1) ? bk : bv;
      float bvv = bp[c];
#pragma unroll
      for (int r = 0; r < 4; ++r) {
        int grow = m0 + wr * 64 + mi * 16 + q * 4 + r;
        float v = acc[mi][ni][r] * ESC_PROJ + bvv;
        size_t o = (size_t)grow * 1024 + c;
        if (seg == 0) {
          f16 hh, ll; splitf16(v * SQf, hh, ll); Qbh[o] = hh; Qbl[o] = ll;
        } else if (seg == 1) {
          f16 hh, ll; splitf16(v * SQf, hh, ll); Kbh[o] = hh; Kbl[o] = ll;
        } else {
          Vh16[o] = (f16)(v * SVf);
        }
      }
    }
}

// ------- fused: blocks 0-1023 transpose V; 1024-1279 ksum partials (hi-only) -------
__global__ __launch_bounds__(256) void vk_fused(
    const f16* __restrict__ Vh16, f16* __restrict__ out,
    const f16* __restrict__ Kh, float* __restrict__ ksum) {
  __shared__ f16 ts[64][72];
  __shared__ float red[4][64];
  const int t = threadIdx.x;
  const int bid = blockIdx.x;
  if (bid < 1024) {
    const int l0 = (bid & 31) * 64;
    const int bh = bid >> 5, b = bh >> 4, h = bh & 15;
#pragma unroll
    for (int c = 0; c < 2; ++c) {
      int e = c * 256 + t; int row = e >> 3, cg = e & 7;
      *(uint4*)&ts[row][cg * 8] =
          *(const uint4*)&Vh16[((size_t)b * Ln + l0 + row) * Dn + h * DHn + cg * 8];
    }
    __syncthreads();
#pragma unroll
    for (int c = 0; c < 2; ++c) {
      int e = c * 256 + t; int drow = e >> 3, lg = e & 7;
      f16 tmp[8];
#pragma unroll
      for (int j = 0; j < 8; ++j) tmp[j] = ts[lg * 8 + j][drow];
      *(uint4*)&out[((size_t)bh * DHn + drow) * Ln + l0 + lg * 8] = *(uint4*)tmp;
    }
    return;
  }
  const int r0 = bid - 1024;                // 0..255
  const int bx = r0 & 7, bh = r0 >> 3, b = bh >> 4, h = bh & 15;
  const int d = t & 63, seg = t >> 6;
  float s = 0.f;
  const int lbase = bx * 256 + seg * 64;
  for (int r = 0; r < 64; ++r) {
    size_t o = ((size_t)b * Ln + lbase + r) * Dn + h * DHn + d;
    s += (float)Kh[o];
  }
  red[seg][d] = s;
  __syncthreads();
  if (t < 64) atomicAdd(&ksum[bh * DHn + t], red[0][t] + red[1][t] + red[2][t] + red[3][t]);
}

// ------- A-single MFMA GEMM (out proj): 128x64 tiles, XCD-swizzled, T14 dbuf -------
// dbuf kept: occupancy-neutral here (2x16KB=32KB at (256,4) -> still 4 blocks/CU).
#define A1_STAGE_TILE(BUF, KOFF) do { \
    const f16* s0_ = A + (size_t)m0 * K + (KOFF); \
    const f16* s2_ = Bth + (size_t)n0 * K + (KOFF); \
    const f16* s3_ = Btl + (size_t)n0 * K + (KOFF); \
    _Pragma("unroll") for (int c_ = 0; c_ < 2; ++c_) { \
      int f_ = (c_ * 256 + t) * 8; int row_ = f_ >> 5, col_ = f_ & 31; \
      gl_lds16(s0_ + (size_t)row_ * K + col_, &sA[BUF][f_]); \
    } \
    { int f_ = t * 8; int row_ = f_ >> 5, col_ = f_ & 31; \
      gl_lds16(s2_ + (size_t)row_ * K + col_, &sBh[BUF][f_]); \
      gl_lds16(s3_ + (size_t)row_ * K + col_, &sBl[BUF][f_]); } } while (0)

__global__ __launch_bounds__(256, 4) void gemm_a1(
    const f16* __restrict__ A,
    const f16* __restrict__ Bth, const f16* __restrict__ Btl,
    const float* __restrict__ bias, float escale,
    float* __restrict__ Cf, int M, int N, int K) {
  __shared__ f16 sA[2][128 * 32], sBh[2][64 * 32], sBl[2][64 * 32];
  const int t = threadIdx.x;
  const int w = t >> 6, lane = t & 63, lm = lane & 15, q = lane >> 4;
  const int wr = w >> 1, wc = w & 1;
  int ob = blockIdx.x;
  int wg = (ob & 7) * 64 + (ob >> 3);          // XCD swizzle (512 % 8 == 0, bijective)
  const int n0 = (wg & 15) * 64, m0 = (wg >> 4) * 128;
  f32x4 acc[4][2] = {};
  A1_STAGE_TILE(0, 0);
  asm volatile("s_waitcnt vmcnt(0)" ::: "memory");
  __builtin_amdgcn_s_barrier();
  for (int k0 = 0; k0 < K; k0 += 32) {
    const int cur = (k0 >> 5) & 1;
    if (k0 + 32 < K) A1_STAGE_TILE(cur ^ 1, k0 + 32);
    f16x8 a_[4], b_h[2], b_l[2];
#pragma unroll
    for (int mi = 0; mi < 4; ++mi)
      a_[mi] = *(const f16x8*)&sA[cur][(wr * 64 + mi * 16 + lm) * 32 + q * 8];
#pragma unroll
    for (int ni = 0; ni < 2; ++ni) {
      int r = (wc * 32 + ni * 16 + lm) * 32 + q * 8;
      b_h[ni] = *(const f16x8*)&sBh[cur][r];
      b_l[ni] = *(const f16x8*)&sBl[cur][r];
    }
#pragma unroll
    for (int mi = 0; mi < 4; ++mi)
#pragma unroll
      for (int ni = 0; ni < 2; ++ni) {
        acc[mi][ni] = MFMA(a_[mi], b_h[ni], acc[mi][ni]);
        acc[mi][ni] = MFMA(a_[mi], b_l[ni], acc[mi][ni]);
      }
    asm volatile("s_waitcnt vmcnt(0) lgkmcnt(0)" ::: "memory");
    __builtin_amdgcn_s_barrier();
  }
#pragma unroll
  for (int mi = 0; mi < 4; ++mi)
#pragma unroll
    for (int ni = 0; ni < 2; ++ni) {
      int gcol = n0 + wc * 32 + ni * 16 + lm;
      float bvv = bias[gcol];
#pragma unroll
      for (int r = 0; r < 4; ++r) {
        int grow = m0 + wr * 64 + mi * 16 + q * 4 + r;
        Cf[(size_t)grow * N + gcol] = acc[mi][ni][r] * escale + bvv;
      }
    }
}

// ---------------- stats: hi-only row max (MFMA) + spars = max - mean ----------------
// Single-buffer serialized (r7 form): at 34.5KB LDS this runs 4 blocks/CU, and
// cross-block overlap hides staging; the dbuf variant cut occupancy and lost (r8/r9).
// LDS chunk-swizzled (c16 ^= row&7, pre-swizzled global source).
__global__ __launch_bounds__(256, 2) void attn_stats_mfma(
    const f16* __restrict__ Qh, const f16* __restrict__ Kh,
    const float* __restrict__ ksum,
    float* __restrict__ row_max, float* __restrict__ spars) {
  __shared__ f16 sQh[128 * 64], sKh[128 * 64];
  __shared__ float redm[128][5];
  const int t = threadIdx.x;
  const int w = t >> 6, lane = t & 63, lm = lane & 15, q = lane >> 4;
  const int bh = blockIdx.y, b = bh >> 4, h = bh & 15;
  const int q0 = blockIdx.x * 128;
  const f16* qsh = Qh + ((size_t)b * Ln + q0) * Dn + h * DHn;
#pragma unroll
  for (int c = 0; c < 4; ++c) {
    int f = (c * 256 + t) * 8; int row = f >> 6, c16 = (f >> 3) & 7;
    size_t go = (size_t)row * Dn + ((c16 ^ (row & 7)) << 3);
    gl_lds16(qsh + go, &sQh[f]);
  }
  __syncthreads();
  f16x8 a_h[8][2];
#pragma unroll
  for (int mi = 0; mi < 8; ++mi)
#pragma unroll
    for (int ks = 0; ks < 2; ++ks) {
      int row = mi * 16 + lm;
      int r = row * 64 + (((ks * 4 + q) ^ (row & 7)) << 3);
      a_h[mi][ks] = *(const f16x8*)&sQh[r];
    }
  float rmax[8][4];
#pragma unroll
  for (int mi = 0; mi < 8; ++mi)
#pragma unroll
    for (int r = 0; r < 4; ++r) rmax[mi][r] = -1e30f;

  for (int kt = 0; kt < Ln / 128; ++kt) {
    __syncthreads();
    const f16* ksh = Kh + ((size_t)b * Ln + kt * 128) * Dn + h * DHn;
#pragma unroll
    for (int c = 0; c < 4; ++c) {
      int f = (c * 256 + t) * 8; int row = f >> 6, c16 = (f >> 3) & 7;
      size_t go = (size_t)row * Dn + ((c16 ^ (row & 7)) << 3);
      gl_lds16(ksh + go, &sKh[f]);
    }
    __syncthreads();
#pragma unroll
    for (int ni = 0; ni < 2; ++ni) {
      int bcol = (w * 2 + ni) * 16;
      f16x8 b_h[2];
#pragma unroll
      for (int ks = 0; ks < 2; ++ks) {
        int row = bcol + lm;
        int r = row * 64 + (((ks * 4 + q) ^ (row & 7)) << 3);
        b_h[ks] = *(const f16x8*)&sKh[r];
      }
#pragma unroll
      for (int mi = 0; mi < 8; ++mi) {
        f32x4 acc = {0.f, 0.f, 0.f, 0.f};
        __builtin_amdgcn_s_setprio(1);
        acc = MFMA(a_h[mi][0], b_h[0], acc);
        acc = MFMA(a_h[mi][1], b_h[1], acc);
        __builtin_amdgcn_s_setprio(0);
#pragma unroll
        for (int r = 0; r < 4; ++r) rmax[mi][r] = fmaxf(rmax[mi][r], acc[r]);
      }
    }
  }
#pragma unroll
  for (int mi = 0; mi < 8; ++mi)
#pragma unroll
    for (int r = 0; r < 4; ++r) {
      float v = rmax[mi][r];
      v = fmaxf(v, __shfl_xor(v, 1)); v = fmaxf(v, __shfl_xor(v, 2));
      v = fmaxf(v, __shfl_xor(v, 4)); v = fmaxf(v, __shfl_xor(v, 8));
      if (lm == 0) redm[mi * 16 + q * 4 + r][w] = v;
    }
  __syncthreads();
  if (t < 128) {
    float m = fmaxf(fmaxf(redm[t][0], redm[t][1]), fmaxf(redm[t][2], redm[t][3]));
    float dot = 0.f;
    const float* kp = ksum + bh * DHn;
#pragma unroll
    for (int d = 0; d < 64; ++d) {
      int idx = t * 64 + ((((d >> 3) ^ (t & 7)) << 3) | (d & 7));
      dot += (float)sQh[idx] * kp[d];
    }
    row_max[(size_t)bh * Ln + q0 + t] = m * PSC;
    spars[(size_t)bh * Ln + q0 + t] = m * PSC - dot * (PSC / (float)Ln);
  }
}

// ---------------- bitonic sort, 1024 threads (1 pair per thread per step) ----------------
__global__ __launch_bounds__(1024) void topk_sort(
    const float* __restrict__ spars, int* __restrict__ top_idx, int* __restrict__ wrow) {
  __shared__ unsigned long long keys[Ln];   // 16 KB
  const int t = threadIdx.x;
  const int bh = blockIdx.x;
  for (int i = t; i < Ln; i += 1024) {
    unsigned u = __float_as_uint(spars[(size_t)bh * Ln + i]);
    u = (u & 0x80000000u) ? ~u : (u | 0x80000000u);
    u = ~u;
    keys[i] = ((unsigned long long)u << 32) | (unsigned)i;
  }
  __syncthreads();
  for (int k = 2; k <= Ln; k <<= 1) {
    for (int j = k >> 1; j > 0; j >>= 1) {
      int i = ((t & ~(j - 1)) << 1) | (t & (j - 1));
      int ixj = i | j;
      unsigned long long a = keys[i], bb = keys[ixj];
      bool up = ((i & k) == 0);
      if ((a > bb) == up) { keys[i] = bb; keys[ixj] = a; }
      __syncthreads();
    }
  }
  for (int u = t; u < Un - WHALF; u += 1024)
    top_idx[(size_t)bh * Un + u] = (int)(keys[u] & 0xFFFFFFFFu);
  if (t < WIN) wrow[bh * WIN + t] = (int)(keys[Un - WHALF + t] & 0xFFFFFFFFu);
}

// ------- hi+lo (~22-bit) sparsity partials for the WIN window rows, K read ONCE -------
// grid (8, BHn), 256 thr.  Block owns keys [bx*256, bx*256+256), one per thread;
// all WIN q-rows staged in LDS (reconstructed fp32).  Per-key dot in d-ascending
// FMA order (deterministic).  topk_final folds the 8 partials.
__global__ __launch_bounds__(256) void refine_part(
    const f16* __restrict__ Qbh, const f16* __restrict__ Qbl,
    const f16* __restrict__ Kbh, const f16* __restrict__ Kbl,
    const int* __restrict__ wrow,
    float* __restrict__ pmaxf, float* __restrict__ psum) {
  __shared__ float qs[WIN][68];            // stride 68 floats (272B)
  __shared__ float redm[4][WIN], reds[4][WIN];
  const int t = threadIdx.x;
  const int bx = blockIdx.x, bh = blockIdx.y, b = bh >> 4, h = bh & 15;
  {
    int j = t >> 3, d0 = (t & 7) * 8;      // 32 rows x 8 threads x 8 elems
    int qi = wrow[bh * WIN + j];
    size_t o = ((size_t)b * Ln + qi) * Dn + h * DHn + d0;
    f16x8 vh = *(const f16x8*)&Qbh[o];
    f16x8 vl = *(const f16x8*)&Qbl[o];
#pragma unroll
    for (int e = 0; e < 8; ++e) qs[j][d0 + e] = (float)vh[e] + (float)vl[e];
  }
  __syncthreads();
  const int ki = bx * 256 + t;
  const size_t ko = ((size_t)b * Ln + ki) * Dn + h * DHn;
  float s[WIN];
#pragma unroll
  for (int j = 0; j < WIN; ++j) s[j] = 0.f;
  for (int d0 = 0; d0 < 64; d0 += 8) {
    f16x8 vh = *(const f16x8*)&Kbh[ko + d0];
    f16x8 vl = *(const f16x8*)&Kbl[ko + d0];
    float kf[8];
#pragma unroll
    for (int e = 0; e < 8; ++e) kf[e] = (float)vh[e] + (float)vl[e];
#pragma unroll
    for (int e = 0; e < 8; ++e)
#pragma unroll
      for (int j = 0; j < WIN; ++j)
        s[j] = fmaf(kf[e], qs[j][d0 + e], s[j]);
  }
  const int w = t >> 6, lane = t & 63;
#pragma unroll
  for (int j = 0; j < WIN; ++j) {
    float mx = s[j], sm = s[j];
#pragma unroll
    for (int off = 1; off < 64; off <<= 1) {
      mx = fmaxf(mx, __shfl_xor(mx, off));
      sm += __shfl_xor(sm, off);
    }
    if (lane == 0) { redm[w][j] = mx; reds[w][j] = sm; }
  }
  __syncthreads();
  if (t < WIN) {
    float mx = fmaxf(fmaxf(redm[0][t], redm[1][t]), fmaxf(redm[2][t], redm[3][t]));
    float sm = reds[0][t] + reds[1][t] + reds[2][t] + reds[3][t];
    size_t o = ((size_t)bh * WIN + t) * 8 + bx;
    pmaxf[o] = mx;
    psum[o] = sm;
  }
}

// ------- fold refine partials -> spx (PSC folds the SQf^2 scale); pick top-WHALF -------
__global__ __launch_bounds__(64) void topk_final(
    const float* __restrict__ pmaxf, const float* __restrict__ psum,
    const int* __restrict__ wrow, int* __restrict__ top_idx) {
  __shared__ float spxL[WIN];
  const int bh = blockIdx.x;
  const int t = threadIdx.x;
  if (t < WIN) {
    float m = -1e30f, s = 0.f;
#pragma unroll
    for (int p = 0; p < 8; ++p) {
      size_t o = ((size_t)bh * WIN + t) * 8 + p;
      m = fmaxf(m, pmaxf[o]);
      s += psum[o];
    }
    spxL[t] = PSC * (m - s * (1.0f / (float)Ln));
  }
  __syncthreads();
  if (t != 0) return;
  float v[WIN]; int r[WIN];
#pragma unroll
  for (int j = 0; j < WIN; ++j) { v[j] = spxL[j]; r[j] = wrow[bh * WIN + j]; }
  unsigned taken = 0;
  for (int s2 = 0; s2 < WHALF; ++s2) {
    int best = -1;
    for (int j = 0; j < WIN; ++j) {
      if (taken & (1u << j)) continue;
      if (best < 0 || v[j] > v[best] || (v[j] == v[best] && r[j] < r[best])) best = j;
    }
    taken |= 1u << best;
    top_idx[(size_t)bh * Un + (Un - WHALF) + s2] = r[best];
  }
}

// ------- selected-row attention, MERGED halves (32 K-tiles), T14 dbuf prefetch -------
// grid (ceil(U/64), BH).  Per iter: issue next tile's global_load_lds into buf^1,
// QK+softmax on buf (lgkmcnt-only mid barrier; prefetch stays in flight), PV,
// vmcnt(0)+barrier at iter end.  Epilogue normalizes and scatters to AOh directly
// (pO/pD round-trip and attn_combine eliminated).
__global__ __launch_bounds__(256, 3) void attn_sel(
    const f16* __restrict__ Qh, const f16* __restrict__ Kh,
    const f16* __restrict__ Vth,
    const int* __restrict__ topi, const float* __restrict__ row_max,
    f16* __restrict__ AOh) {
  __shared__ f16 sK[2][64 * 64], sV[2][64 * 64];
  __shared__ f16 sQP[64 * QPS];  // Q staged (stride QPS), then P (stride QPS)
  __shared__ float rmL[64];
  __shared__ int qxL[64];
  __shared__ float dred[64][5];
  const int t = threadIdx.x;
  const int w = t >> 6, lane = t & 63, lm = lane & 15, q = lane >> 4;
  const int bh = blockIdx.y, b = bh >> 4, h = bh & 15;
  const int u0 = blockIdx.x * 64;
  const int nrows = (Un - u0 < 64) ? (Un - u0) : 64;
  if (t < 64) {
    int qi = topi[(size_t)bh * Un + ((t < nrows) ? (u0 + t) : 0)];
    qxL[t] = qi;
    rmL[t] = row_max[(size_t)bh * Ln + qi];
  }
  __syncthreads();
#pragma unroll
  for (int c = 0; c < 2; ++c) {
    int f = (c * 256 + t) * 8; int row = f >> 6, col = f & 63;
    size_t go = ((size_t)b * Ln + qxL[row]) * Dn + h * DHn + col;
    *(uint4*)&sQP[row * QPS + col] = *(const uint4*)&Qh[go];
  }
  __syncthreads();
  f16x8 aq[4][2];
#pragma unroll
  for (int mi = 0; mi < 4; ++mi)
#pragma unroll
    for (int ks = 0; ks < 2; ++ks)
      aq[mi][ks] = *(const f16x8*)&sQP[(mi * 16 + lm) * QPS + ks * 32 + q * 8];
  f32x4 oacc[4] = {};
  float dacc[4][4] = {};

  const f16* kbase = Kh + (size_t)b * Ln * Dn + h * DHn;
  const f16* vbase = Vth + (size_t)bh * DHn * Ln;

  // prologue: stage tile 0 into buffer 0; drain aq reads + staging, sync
#pragma unroll
  for (int c = 0; c < 2; ++c) {
    int f = (c * 256 + t) * 8; int row = f >> 6, c16 = (f >> 3) & 7;
    int sc = (c16 ^ (row & 7)) << 3;
    gl_lds16(kbase + (size_t)row * Dn + sc, &sK[0][f]);
    gl_lds16(vbase + (size_t)row * Ln + sc, &sV[0][f]);
  }
  asm volatile("s_waitcnt vmcnt(0) lgkmcnt(0)" ::: "memory");
  __builtin_amdgcn_s_barrier();

  for (int kt = 0; kt < 32; ++kt) {
    const int cur = kt & 1;
    f16x8 kb[2];
#pragma unroll
    for (int ks = 0; ks < 2; ++ks) {
      int row = w * 16 + lm;
      kb[ks] = *(const f16x8*)&sK[cur][row * 64 + (((ks * 4 + q) ^ (row & 7)) << 3)];
    }
    if (kt < 31) {  // issue next tile into the other buffer; stays in flight
      const int ln0 = (kt + 1) * 64;
#pragma unroll
      for (int c = 0; c < 2; ++c) {
        int f = (c * 256 + t) * 8; int row = f >> 6, c16 = (f >> 3) & 7;
        int sc = (c16 ^ (row & 7)) << 3;
        gl_lds16(kbase + (size_t)(ln0 + row) * Dn + sc, &sK[cur ^ 1][f]);
        gl_lds16(vbase + (size_t)row * Ln + ln0 + sc, &sV[cur ^ 1][f]);
      }
    }
#pragma unroll
    for (int mi = 0; mi < 4; ++mi) {
      f32x4 acc = {0.f, 0.f, 0.f, 0.f};
      __builtin_amdgcn_s_setprio(1);
      acc = MFMA(aq[mi][0], kb[0], acc);
      acc = MFMA(aq[mi][1], kb[1], acc);
      __builtin_amdgcn_s_setprio(0);
#pragma unroll
      for (int r = 0; r < 4; ++r) {
        int row = mi * 16 + q * 4 + r;
        float p = __expf(acc[r] * PSC - rmL[row]);
        dacc[mi][r] += p;
        sQP[row * QPS + w * 16 + lm] = (f16)(p * SPf);
      }
    }
    // P visible + all LDS reads of buf[cur] drained; vmcnt NOT drained (T4)
    asm volatile("s_waitcnt lgkmcnt(0)" ::: "memory");
    __builtin_amdgcn_s_barrier();
    f16x8 vb[2];
#pragma unroll
    for (int ks = 0; ks < 2; ++ks) {
      int row = w * 16 + lm;
      vb[ks] = *(const f16x8*)&sV[cur][row * 64 + (((ks * 4 + q) ^ (row & 7)) << 3)];
    }
#pragma unroll
    for (int mi = 0; mi < 4; ++mi) {
      f16x8 pf0 = *(const f16x8*)&sQP[(mi * 16 + lm) * QPS + 0 * 32 + q * 8];
      f16x8 pf1 = *(const f16x8*)&sQP[(mi * 16 + lm) * QPS + 1 * 32 + q * 8];
      __builtin_amdgcn_s_setprio(1);
      oacc[mi] = MFMA(pf0, vb[0], oacc[mi]);
      oacc[mi] = MFMA(pf1, vb[1], oacc[mi]);
      __builtin_amdgcn_s_setprio(0);
    }
    // next tile's staging landed on all waves before anyone reads it
    asm volatile("s_waitcnt vmcnt(0)" ::: "memory");
    __builtin_amdgcn_s_barrier();
  }
  // denominators: 4-lane-group shuffle reduce, then cross-wave via LDS
#pragma unroll
  for (int mi = 0; mi < 4; ++mi)
#pragma unroll
    for (int r = 0; r < 4; ++r) {
      float v = dacc[mi][r];
      v += __shfl_xor(v, 1); v += __shfl_xor(v, 2);
      v += __shfl_xor(v, 4); v += __shfl_xor(v, 8);
      if (lm == 0) dred[mi * 16 + q * 4 + r][w] = v;
    }
  __syncthreads();
  // normalize + scatter to AOh (thread owns column w*16+lm of its 16 rows)
#pragma unroll
  for (int mi = 0; mi < 4; ++mi)
#pragma unroll
    for (int r = 0; r < 4; ++r) {
      int row = mi * 16 + q * 4 + r;
      if (row < nrows) {
        float dinv = 1.0f / (dred[row][0] + dred[row][1] + dred[row][2] + dred[row][3]);
        AOh[((size_t)b * Ln + qxL[row]) * Dn + h * DHn + w * 16 + lm] =
            (f16)(oacc[mi][r] * dinv);
      }
    }
}

extern "C" void kernel_launch(void* const* d_in, const int* in_sizes, int n_in,
                              void* d_out, int out_size, void* d_ws, size_t ws_size,
                              hipStream_t stream) {
  (void)in_sizes; (void)n_in; (void)out_size; (void)ws_size;
  const float* x  = (const float*)d_in[0];
  const float* Wq = (const float*)d_in[1];
  const float* bq = (const float*)d_in[2];
  const float* Wk = (const float*)d_in[3];
  const float* bk = (const float*)d_in[4];
  const float* Wv = (const float*)d_in[5];
  const float* bv = (const float*)d_in[6];
  const float* Wo = (const float*)d_in[7];
  const float* bo = (const float*)d_in[8];
  float* out = (float*)d_out;

  uint8_t* p = (uint8_t*)d_ws;
  const size_t NE = (size_t)Bn * Ln * Dn;          // 4 Mi elements
  f16* xh = (f16*)p;  p += NE * 2;
  f16* xl = (f16*)p;  p += NE * 2;
  f16* Wt_h = (f16*)p; p += (size_t)4096 * Dn * 2;   // rows 0-3071: QKV cat; 3072-4095: Wo
  f16* Wt_l = (f16*)p; p += (size_t)4096 * Dn * 2;
  f16* Qbh = (f16*)p; p += NE * 2;
  f16* Qbl = (f16*)p; p += NE * 2;
  f16* Kbh = (f16*)p; p += NE * 2;
  f16* Kbl = (f16*)p; p += NE * 2;
  f16* Vh16 = (f16*)p; p += NE * 2;
  f16* Vth  = (f16*)p; p += NE * 2;
  float* rowmax = (float*)p; p += (size_t)BHn * Ln * 4;
  float* spars  = (float*)p; p += (size_t)BHn * Ln * 4;
  float* ksum   = (float*)p; p += (size_t)BHn * DHn * 4;
  int* topi     = (int*)p;   p += (size_t)BHn * Un * 4;
  int* wrow     = (int*)p;   p += (size_t)BHn * WIN * 4;
  float* pmaxf  = (float*)p; p += (size_t)BHn * WIN * 8 * 4;
  float* psum   = (float*)p; p += (size_t)BHn * WIN * 8 * 4;
  f16* AOh = xh;   // alias: x split dead after QKV GEMM

  dim3 blk(256);
  hipLaunchKernelGGL(prep_fused, dim3(4096 + 1024), blk, 0, stream,
                     x, xh, xl, (int)(NE / 4), Wq, Wk, Wv, Wo, Wt_h, Wt_l);
  hipLaunchKernelGGL(gemm_qkv, dim3(24, 32), blk, 0, stream, xh, xl, Wt_h, Wt_l,
                     bq, bk, bv, Qbh, Qbl, Kbh, Kbl, Vh16, Dn);
  hipMemsetAsync(ksum, 0, (size_t)BHn * DHn * 4, stream);
  hipLaunchKernelGGL(vk_fused, dim3(1024 + 256), blk, 0, stream, Vh16, Vth, Kbh, ksum);
  hipLaunchKernelGGL(attn_stats_mfma, dim3(Ln / 128, BHn), blk, 0, stream,
                     Qbh, Kbh, ksum, rowmax, spars);
  hipLaunchKernelGGL(topk_sort, dim3(BHn), dim3(1024), 0, stream, spars, topi, wrow);
  hipLaunchKernelGGL(refine_part, dim3(8, BHn), blk, 0, stream,
                     Qbh, Qbl, Kbh, Kbl, wrow, pmaxf, psum);
  hipLaunchKernelGGL(topk_final, dim3(BHn), dim3(64), 0, stream, pmaxf, psum, wrow, topi);
  hipMemsetAsync(AOh, 0, NE * 2, stream);
  hipLaunchKernelGGL(attn_sel, dim3((Un + 63) / 64, BHn), blk, 0, stream,
                     Qbh, Kbh, Vth, topi, rowmax, AOh);
  hipLaunchKernelGGL(gemm_a1, dim3(512), blk, 0, stream, AOh,
                     Wt_h + (size_t)3072 * Dn, Wt_l + (size_t)3072 * Dn, bo,
                     ESC_OUT, out, Bn * Ln, Dn, Dn);
}

// Round 12
// 374.962 us; speedup vs baseline: 1.0061x; 1.0061x over previous
//
#include <hip/hip_runtime.h>
#include <math.h>
#include <stdint.h>

#define Bn 2
#define Ln 2048
#define Dn 1024
#define Hn 16
#define DHn 64
#define Un 1228
#define BHn (Bn*Hn)
#define SCALE 0.125f
// refine window: exact re-rank of WIN rows around the top-k cut (hi+lo ~22-bit)
#define WIN 32
#define WHALF 16
// pre-split power-of-2 scales (dodge fp16 subnormal flush on lo terms)
#define SXf 16.0f     // x
#define SWf 256.0f    // all W
#define SQf 16.0f     // Q, K
#define SVf 16.0f     // V
#define SPf 16.0f     // softmax P
#define ESC_PROJ (1.0f / 4096.0f)    // 1/(SX*SW)
#define ESC_OUT  (1.0f / 65536.0f)   // 1/(SPf*SVf*SWf)
#define PSC (SCALE / 256.0f)         // score unscale: 1/(SQ*SQ) * SCALE
#define QPS 88                        // P/Q LDS stride (176B: 2-way banks)

typedef _Float16 f16;
typedef __attribute__((ext_vector_type(8))) _Float16 f16x8;
typedef __attribute__((ext_vector_type(4))) float f32x4;
struct h4s { f16 x, y, z, w; };

__device__ __forceinline__ void splitf16(float f, f16& hi, f16& lo) {
  hi = (f16)f;                 // RTNE
  lo = (f16)(f - (float)hi);   // residual, ~22 mantissa bits total
}

// async global->LDS, 16B per lane (wave-uniform base + lane*16)
__device__ __forceinline__ void gl_lds16(const void* g, void* l) {
  __builtin_amdgcn_global_load_lds(
      (const __attribute__((address_space(1))) void*)g,
      (__attribute__((address_space(3))) void*)l, 16, 0, 0);
}

#define MFMA(a, b, c) __builtin_amdgcn_mfma_f32_16x16x32_f16((a), (b), (c), 0, 0, 0)

// ------- fused prep: blocks 0-4095 split x; 4096-5119 transpose+split W0..W3 -------
__global__ __launch_bounds__(256) void prep_fused(
    const float* __restrict__ x, f16* __restrict__ xh, f16* __restrict__ xl, int n4,
    const float* __restrict__ W0, const float* __restrict__ W1,
    const float* __restrict__ W2, const float* __restrict__ W3,
    f16* __restrict__ oh, f16* __restrict__ ol) {
  __shared__ float ts[64][65];
  const int t = threadIdx.x;
  const int bid = blockIdx.x;
  if (bid < 4096) {
    int i = bid * 256 + t;
    if (i >= n4) return;
    float4 v = ((const float4*)x)[i];
    h4s h, l;
    splitf16(v.x * SXf, h.x, l.x); splitf16(v.y * SXf, h.y, l.y);
    splitf16(v.z * SXf, h.z, l.z); splitf16(v.w * SXf, h.w, l.w);
    ((h4s*)xh)[i] = h; ((h4s*)xl)[i] = l;
    return;
  }
  const int r = bid - 4096;                 // 0..1023
  const int r0 = (r & 15) * 64, c0 = ((r >> 4) & 15) * 64, z = r >> 8;
  const float* in = (z == 0) ? W0 : (z == 1) ? W1 : (z == 2) ? W2 : W3;
#pragma unroll
  for (int c = 0; c < 4; ++c) {
    int f = (c * 256 + t) * 4; int row = f >> 6, col = f & 63;
    float4 v = *(const float4*)&in[(size_t)(r0 + row) * Dn + c0 + col];
    ts[row][col] = v.x; ts[row][col + 1] = v.y; ts[row][col + 2] = v.z; ts[row][col + 3] = v.w;
  }
  __syncthreads();
#pragma unroll
  for (int c = 0; c < 4; ++c) {
    int f = (c * 256 + t) * 4; int crow = f >> 6, rcol = f & 63;
    h4s h, l;
    splitf16(ts[rcol + 0][crow] * SWf, h.x, l.x);
    splitf16(ts[rcol + 1][crow] * SWf, h.y, l.y);
    splitf16(ts[rcol + 2][crow] * SWf, h.z, l.z);
    splitf16(ts[rcol + 3][crow] * SWf, h.w, l.w);
    size_t o = (size_t)(z * 1024 + c0 + crow) * Dn + r0 + rcol;
    *(h4s*)&oh[o] = h; *(h4s*)&ol[o] = l;
  }
}

// ------- fused QKV GEMM (2-phase, proven r8 form): [4096 x 3072] -------
// Single-buffer: implicit wave-level overlap at ~25% occupancy already hides the
// staging latency (m114); explicit dbuf costs occupancy and regressed (r9).
// Epilogue: Q/K hi/lo f16 pairs; V f16.
__global__ void gemm_qkv(
    const f16* __restrict__ Ah, const f16* __restrict__ Al,
    const f16* __restrict__ Bth, const f16* __restrict__ Btl,
    const float* __restrict__ bq, const float* __restrict__ bk, const float* __restrict__ bv,
    f16* __restrict__ Qbh, f16* __restrict__ Qbl,
    f16* __restrict__ Kbh, f16* __restrict__ Kbl,
    f16* __restrict__ Vh16, int K) {
  __shared__ f16 sAh[128 * 32], sAl[128 * 32], sBh[128 * 32], sBl[128 * 32];
  const int t = threadIdx.x;
  const int w = t >> 6, lane = t & 63, lm = lane & 15, q = lane >> 4;
  const int wr = w >> 1, wc = w & 1;
  const int n0 = blockIdx.x * 128, m0 = blockIdx.y * 128;
  f32x4 acc[4][4] = {};
  for (int k0 = 0; k0 < K; k0 += 32) {
    const f16* s0 = Ah + (size_t)m0 * K + k0;
    const f16* s1 = Al + (size_t)m0 * K + k0;
    const f16* s2 = Bth + (size_t)n0 * K + k0;
    const f16* s3 = Btl + (size_t)n0 * K + k0;
#pragma unroll
    for (int c = 0; c < 2; ++c) {
      int f = (c * 256 + t) * 8; int row = f >> 5, col = f & 31;
      size_t go = (size_t)row * K + col;
      gl_lds16(s0 + go, &sAh[f]);
      gl_lds16(s1 + go, &sAl[f]);
      gl_lds16(s2 + go, &sBh[f]);
      gl_lds16(s3 + go, &sBl[f]);
    }
    __syncthreads();
    f16x8 a_h[4], a_l[4], b_h[4], b_l[4];
#pragma unroll
    for (int mi = 0; mi < 4; ++mi) {
      int r = (wr * 64 + mi * 16 + lm) * 32 + q * 8;
      a_h[mi] = *(const f16x8*)&sAh[r];
      a_l[mi] = *(const f16x8*)&sAl[r];
    }
#pragma unroll
    for (int ni = 0; ni < 4; ++ni) {
      int r = (wc * 64 + ni * 16 + lm) * 32 + q * 8;
      b_h[ni] = *(const f16x8*)&sBh[r];
      b_l[ni] = *(const f16x8*)&sBl[r];
    }
#pragma unroll
    for (int mi = 0; mi < 4; ++mi)
#pragma unroll
      for (int ni = 0; ni < 4; ++ni) {
        acc[mi][ni] = MFMA(a_h[mi], b_h[ni], acc[mi][ni]);
        acc[mi][ni] = MFMA(a_h[mi], b_l[ni], acc[mi][ni]);
        acc[mi][ni] = MFMA(a_l[mi], b_h[ni], acc[mi][ni]);
      }
    __syncthreads();
  }
#pragma unroll
  for (int mi = 0; mi < 4; ++mi)
#pragma unroll
    for (int ni = 0; ni < 4; ++ni) {
      int nglob = n0 + wc * 64 + ni * 16;         // 16-aligned, wave-uniform segment
      int seg = nglob >> 10;
      int c = (nglob & 1023) + lm;                // column within segment
      const float* bp = (seg == 0) ? bq : (seg == 1) ? bk : bv;
      float bvv = bp[c];
#pragma unroll
      for (int r = 0; r < 4; ++r) {
        int grow = m0 + wr * 64 + mi * 16 + q * 4 + r;
        float v = acc[mi][ni][r] * ESC_PROJ + bvv;
        size_t o = (size_t)grow * 1024 + c;
        if (seg == 0) {
          f16 hh, ll; splitf16(v * SQf, hh, ll); Qbh[o] = hh; Qbl[o] = ll;
        } else if (seg == 1) {
          f16 hh, ll; splitf16(v * SQf, hh, ll); Kbh[o] = hh; Kbl[o] = ll;
        } else {
          Vh16[o] = (f16)(v * SVf);
        }
      }
    }
}

// ------- fused: blocks 0-1023 transpose V; 1024-1279 ksum partials (hi-only) -------
__global__ __launch_bounds__(256) void vk_fused(
    const f16* __restrict__ Vh16, f16* __restrict__ out,
    const f16* __restrict__ Kh, float* __restrict__ ksum) {
  __shared__ f16 ts[64][72];
  __shared__ float red[4][64];
  const int t = threadIdx.x;
  const int bid = blockIdx.x;
  if (bid < 1024) {
    const int l0 = (bid & 31) * 64;
    const int bh = bid >> 5, b = bh >> 4, h = bh & 15;
#pragma unroll
    for (int c = 0; c < 2; ++c) {
      int e = c * 256 + t; int row = e >> 3, cg = e & 7;
      *(uint4*)&ts[row][cg * 8] =
          *(const uint4*)&Vh16[((size_t)b * Ln + l0 + row) * Dn + h * DHn + cg * 8];
    }
    __syncthreads();
#pragma unroll
    for (int c = 0; c < 2; ++c) {
      int e = c * 256 + t; int drow = e >> 3, lg = e & 7;
      f16 tmp[8];
#pragma unroll
      for (int j = 0; j < 8; ++j) tmp[j] = ts[lg * 8 + j][drow];
      *(uint4*)&out[((size_t)bh * DHn + drow) * Ln + l0 + lg * 8] = *(uint4*)tmp;
    }
    return;
  }
  const int r0 = bid - 1024;                // 0..255
  const int bx = r0 & 7, bh = r0 >> 3, b = bh >> 4, h = bh & 15;
  const int d = t & 63, seg = t >> 6;
  float s = 0.f;
  const int lbase = bx * 256 + seg * 64;
  for (int r = 0; r < 64; ++r) {
    size_t o = ((size_t)b * Ln + lbase + r) * Dn + h * DHn + d;
    s += (float)Kh[o];
  }
  red[seg][d] = s;
  __syncthreads();
  if (t < 64) atomicAdd(&ksum[bh * DHn + t], red[0][t] + red[1][t] + red[2][t] + red[3][t]);
}

// ------- A-single MFMA GEMM (out proj): 128x64 tiles, XCD-swizzled, T14 dbuf -------
// dbuf kept: occupancy-neutral here (2x16KB=32KB at (256,4) -> still 4 blocks/CU).
#define A1_STAGE_TILE(BUF, KOFF) do { \
    const f16* s0_ = A + (size_t)m0 * K + (KOFF); \
    const f16* s2_ = Bth + (size_t)n0 * K + (KOFF); \
    const f16* s3_ = Btl + (size_t)n0 * K + (KOFF); \
    _Pragma("unroll") for (int c_ = 0; c_ < 2; ++c_) { \
      int f_ = (c_ * 256 + t) * 8; int row_ = f_ >> 5, col_ = f_ & 31; \
      gl_lds16(s0_ + (size_t)row_ * K + col_, &sA[BUF][f_]); \
    } \
    { int f_ = t * 8; int row_ = f_ >> 5, col_ = f_ & 31; \
      gl_lds16(s2_ + (size_t)row_ * K + col_, &sBh[BUF][f_]); \
      gl_lds16(s3_ + (size_t)row_ * K + col_, &sBl[BUF][f_]); } } while (0)

__global__ __launch_bounds__(256, 4) void gemm_a1(
    const f16* __restrict__ A,
    const f16* __restrict__ Bth, const f16* __restrict__ Btl,
    const float* __restrict__ bias, float escale,
    float* __restrict__ Cf, int M, int N, int K) {
  __shared__ f16 sA[2][128 * 32], sBh[2][64 * 32], sBl[2][64 * 32];
  const int t = threadIdx.x;
  const int w = t >> 6, lane = t & 63, lm = lane & 15, q = lane >> 4;
  const int wr = w >> 1, wc = w & 1;
  int ob = blockIdx.x;
  int wg = (ob & 7) * 64 + (ob >> 3);          // XCD swizzle (512 % 8 == 0, bijective)
  const int n0 = (wg & 15) * 64, m0 = (wg >> 4) * 128;
  f32x4 acc[4][2] = {};
  A1_STAGE_TILE(0, 0);
  asm volatile("s_waitcnt vmcnt(0)" ::: "memory");
  __builtin_amdgcn_s_barrier();
  for (int k0 = 0; k0 < K; k0 += 32) {
    const int cur = (k0 >> 5) & 1;
    if (k0 + 32 < K) A1_STAGE_TILE(cur ^ 1, k0 + 32);
    f16x8 a_[4], b_h[2], b_l[2];
#pragma unroll
    for (int mi = 0; mi < 4; ++mi)
      a_[mi] = *(const f16x8*)&sA[cur][(wr * 64 + mi * 16 + lm) * 32 + q * 8];
#pragma unroll
    for (int ni = 0; ni < 2; ++ni) {
      int r = (wc * 32 + ni * 16 + lm) * 32 + q * 8;
      b_h[ni] = *(const f16x8*)&sBh[cur][r];
      b_l[ni] = *(const f16x8*)&sBl[cur][r];
    }
#pragma unroll
    for (int mi = 0; mi < 4; ++mi)
#pragma unroll
      for (int ni = 0; ni < 2; ++ni) {
        acc[mi][ni] = MFMA(a_[mi], b_h[ni], acc[mi][ni]);
        acc[mi][ni] = MFMA(a_[mi], b_l[ni], acc[mi][ni]);
      }
    asm volatile("s_waitcnt vmcnt(0) lgkmcnt(0)" ::: "memory");
    __builtin_amdgcn_s_barrier();
  }
#pragma unroll
  for (int mi = 0; mi < 4; ++mi)
#pragma unroll
    for (int ni = 0; ni < 2; ++ni) {
      int gcol = n0 + wc * 32 + ni * 16 + lm;
      float bvv = bias[gcol];
#pragma unroll
      for (int r = 0; r < 4; ++r) {
        int grow = m0 + wr * 64 + mi * 16 + q * 4 + r;
        Cf[(size_t)grow * N + gcol] = acc[mi][ni][r] * escale + bvv;
      }
    }
}

// ---------------- stats: hi-only row max (MFMA) + spars = max - mean ----------------
// Single-buffer serialized (r7 form): at 34.5KB LDS this runs 4 blocks/CU, and
// cross-block overlap hides staging; the dbuf variant cut occupancy and lost (r8/r9).
// LDS chunk-swizzled (c16 ^= row&7, pre-swizzled global source).
__global__ __launch_bounds__(256, 2) void attn_stats_mfma(
    const f16* __restrict__ Qh, const f16* __restrict__ Kh,
    const float* __restrict__ ksum,
    float* __restrict__ row_max, float* __restrict__ spars) {
  __shared__ f16 sQh[128 * 64], sKh[128 * 64];
  __shared__ float redm[128][5];
  const int t = threadIdx.x;
  const int w = t >> 6, lane = t & 63, lm = lane & 15, q = lane >> 4;
  const int bh = blockIdx.y, b = bh >> 4, h = bh & 15;
  const int q0 = blockIdx.x * 128;
  const f16* qsh = Qh + ((size_t)b * Ln + q0) * Dn + h * DHn;
#pragma unroll
  for (int c = 0; c < 4; ++c) {
    int f = (c * 256 + t) * 8; int row = f >> 6, c16 = (f >> 3) & 7;
    size_t go = (size_t)row * Dn + ((c16 ^ (row & 7)) << 3);
    gl_lds16(qsh + go, &sQh[f]);
  }
  __syncthreads();
  f16x8 a_h[8][2];
#pragma unroll
  for (int mi = 0; mi < 8; ++mi)
#pragma unroll
    for (int ks = 0; ks < 2; ++ks) {
      int row = mi * 16 + lm;
      int r = row * 64 + (((ks * 4 + q) ^ (row & 7)) << 3);
      a_h[mi][ks] = *(const f16x8*)&sQh[r];
    }
  float rmax[8][4];
#pragma unroll
  for (int mi = 0; mi < 8; ++mi)
#pragma unroll
    for (int r = 0; r < 4; ++r) rmax[mi][r] = -1e30f;

  for (int kt = 0; kt < Ln / 128; ++kt) {
    __syncthreads();
    const f16* ksh = Kh + ((size_t)b * Ln + kt * 128) * Dn + h * DHn;
#pragma unroll
    for (int c = 0; c < 4; ++c) {
      int f = (c * 256 + t) * 8; int row = f >> 6, c16 = (f >> 3) & 7;
      size_t go = (size_t)row * Dn + ((c16 ^ (row & 7)) << 3);
      gl_lds16(ksh + go, &sKh[f]);
    }
    __syncthreads();
#pragma unroll
    for (int ni = 0; ni < 2; ++ni) {
      int bcol = (w * 2 + ni) * 16;
      f16x8 b_h[2];
#pragma unroll
      for (int ks = 0; ks < 2; ++ks) {
        int row = bcol + lm;
        int r = row * 64 + (((ks * 4 + q) ^ (row & 7)) << 3);
        b_h[ks] = *(const f16x8*)&sKh[r];
      }
#pragma unroll
      for (int mi = 0; mi < 8; ++mi) {
        f32x4 acc = {0.f, 0.f, 0.f, 0.f};
        __builtin_amdgcn_s_setprio(1);
        acc = MFMA(a_h[mi][0], b_h[0], acc);
        acc = MFMA(a_h[mi][1], b_h[1], acc);
        __builtin_amdgcn_s_setprio(0);
#pragma unroll
        for (int r = 0; r < 4; ++r) rmax[mi][r] = fmaxf(rmax[mi][r], acc[r]);
      }
    }
  }
#pragma unroll
  for (int mi = 0; mi < 8; ++mi)
#pragma unroll
    for (int r = 0; r < 4; ++r) {
      float v = rmax[mi][r];
      v = fmaxf(v, __shfl_xor(v, 1)); v = fmaxf(v, __shfl_xor(v, 2));
      v = fmaxf(v, __shfl_xor(v, 4)); v = fmaxf(v, __shfl_xor(v, 8));
      if (lm == 0) redm[mi * 16 + q * 4 + r][w] = v;
    }
  __syncthreads();
  if (t < 128) {
    float m = fmaxf(fmaxf(redm[t][0], redm[t][1]), fmaxf(redm[t][2], redm[t][3]));
    float dot = 0.f;
    const float* kp = ksum + bh * DHn;
#pragma unroll
    for (int d = 0; d < 64; ++d) {
      int idx = t * 64 + ((((d >> 3) ^ (t & 7)) << 3) | (d & 7));
      dot += (float)sQh[idx] * kp[d];
    }
    row_max[(size_t)bh * Ln + q0 + t] = m * PSC;
    spars[(size_t)bh * Ln + q0 + t] = m * PSC - dot * (PSC / (float)Ln);
  }
}

// ---------------- bitonic sort, 1024 threads (1 pair per thread per step) ----------------
__global__ __launch_bounds__(1024) void topk_sort(
    const float* __restrict__ spars, int* __restrict__ top_idx, int* __restrict__ wrow) {
  __shared__ unsigned long long keys[Ln];   // 16 KB
  const int t = threadIdx.x;
  const int bh = blockIdx.x;
  for (int i = t; i < Ln; i += 1024) {
    unsigned u = __float_as_uint(spars[(size_t)bh * Ln + i]);
    u = (u & 0x80000000u) ? ~u : (u | 0x80000000u);
    u = ~u;
    keys[i] = ((unsigned long long)u << 32) | (unsigned)i;
  }
  __syncthreads();
  for (int k = 2; k <= Ln; k <<= 1) {
    for (int j = k >> 1; j > 0; j >>= 1) {
      int i = ((t & ~(j - 1)) << 1) | (t & (j - 1));
      int ixj = i | j;
      unsigned long long a = keys[i], bb = keys[ixj];
      bool up = ((i & k) == 0);
      if ((a > bb) == up) { keys[i] = bb; keys[ixj] = a; }
      __syncthreads();
    }
  }
  for (int u = t; u < Un - WHALF; u += 1024)
    top_idx[(size_t)bh * Un + u] = (int)(keys[u] & 0xFFFFFFFFu);
  if (t < WIN) wrow[bh * WIN + t] = (int)(keys[Un - WHALF + t] & 0xFFFFFFFFu);
}

// ------- hi+lo (~22-bit) sparsity partials for the WIN window rows, K read ONCE -------
__global__ __launch_bounds__(256) void refine_part(
    const f16* __restrict__ Qbh, const f16* __restrict__ Qbl,
    const f16* __restrict__ Kbh, const f16* __restrict__ Kbl,
    const int* __restrict__ wrow,
    float* __restrict__ pmaxf, float* __restrict__ psum) {
  __shared__ float qs[WIN][68];            // stride 68 floats (272B)
  __shared__ float redm[4][WIN], reds[4][WIN];
  const int t = threadIdx.x;
  const int bx = blockIdx.x, bh = blockIdx.y, b = bh >> 4, h = bh & 15;
  {
    int j = t >> 3, d0 = (t & 7) * 8;      // 32 rows x 8 threads x 8 elems
    int qi = wrow[bh * WIN + j];
    size_t o = ((size_t)b * Ln + qi) * Dn + h * DHn + d0;
    f16x8 vh = *(const f16x8*)&Qbh[o];
    f16x8 vl = *(const f16x8*)&Qbl[o];
#pragma unroll
    for (int e = 0; e < 8; ++e) qs[j][d0 + e] = (float)vh[e] + (float)vl[e];
  }
  __syncthreads();
  const int ki = bx * 256 + t;
  const size_t ko = ((size_t)b * Ln + ki) * Dn + h * DHn;
  float s[WIN];
#pragma unroll
  for (int j = 0; j < WIN; ++j) s[j] = 0.f;
  for (int d0 = 0; d0 < 64; d0 += 8) {
    f16x8 vh = *(const f16x8*)&Kbh[ko + d0];
    f16x8 vl = *(const f16x8*)&Kbl[ko + d0];
    float kf[8];
#pragma unroll
    for (int e = 0; e < 8; ++e) kf[e] = (float)vh[e] + (float)vl[e];
#pragma unroll
    for (int e = 0; e < 8; ++e)
#pragma unroll
      for (int j = 0; j < WIN; ++j)
        s[j] = fmaf(kf[e], qs[j][d0 + e], s[j]);
  }
  const int w = t >> 6, lane = t & 63;
#pragma unroll
  for (int j = 0; j < WIN; ++j) {
    float mx = s[j], sm = s[j];
#pragma unroll
    for (int off = 1; off < 64; off <<= 1) {
      mx = fmaxf(mx, __shfl_xor(mx, off));
      sm += __shfl_xor(sm, off);
    }
    if (lane == 0) { redm[w][j] = mx; reds[w][j] = sm; }
  }
  __syncthreads();
  if (t < WIN) {
    float mx = fmaxf(fmaxf(redm[0][t], redm[1][t]), fmaxf(redm[2][t], redm[3][t]));
    float sm = reds[0][t] + reds[1][t] + reds[2][t] + reds[3][t];
    size_t o = ((size_t)bh * WIN + t) * 8 + bx;
    pmaxf[o] = mx;
    psum[o] = sm;
  }
}

// ------- fold refine partials -> spx (PSC folds the SQf^2 scale); pick top-WHALF -------
__global__ __launch_bounds__(64) void topk_final(
    const float* __restrict__ pmaxf, const float* __restrict__ psum,
    const int* __restrict__ wrow, int* __restrict__ top_idx) {
  __shared__ float spxL[WIN];
  const int bh = blockIdx.x;
  const int t = threadIdx.x;
  if (t < WIN) {
    float m = -1e30f, s = 0.f;
#pragma unroll
    for (int p = 0; p < 8; ++p) {
      size_t o = ((size_t)bh * WIN + t) * 8 + p;
      m = fmaxf(m, pmaxf[o]);
      s += psum[o];
    }
    spxL[t] = PSC * (m - s * (1.0f / (float)Ln));
  }
  __syncthreads();
  if (t != 0) return;
  float v[WIN]; int r[WIN];
#pragma unroll
  for (int j = 0; j < WIN; ++j) { v[j] = spxL[j]; r[j] = wrow[bh * WIN + j]; }
  unsigned taken = 0;
  for (int s2 = 0; s2 < WHALF; ++s2) {
    int best = -1;
    for (int j = 0; j < WIN; ++j) {
      if (taken & (1u << j)) continue;
      if (best < 0 || v[j] > v[best] || (v[j] == v[best] && r[j] < r[best])) best = j;
    }
    taken |= 1u << best;
    top_idx[(size_t)bh * Un + (Un - WHALF) + s2] = r[best];
  }
}

// ------- selected-row attention, key-split x2, T14 double-buffered prefetch -------
// grid (ceil(U/64), 2*BH): 1280 blocks keeps all CUs fed (r11's merged 640-block
// variant left ~17% idle and lost).  Per iter: issue next tile into buf^1, QK+softmax
// on buf (lgkmcnt-only mid barrier), PV, vmcnt(0)+barrier at iter end.
__global__ __launch_bounds__(256, 3) void attn_sel_part(
    const f16* __restrict__ Qh, const f16* __restrict__ Kh,
    const f16* __restrict__ Vth,
    const int* __restrict__ topi, const float* __restrict__ row_max,
    float* __restrict__ pO, float* __restrict__ pD) {
  __shared__ f16 sK[2][64 * 64], sV[2][64 * 64];
  __shared__ f16 sQP[64 * QPS];  // Q staged (stride QPS), then P (stride QPS)
  __shared__ float rmL[64];
  __shared__ int qxL[64];
  __shared__ float dred[64][5];
  const int t = threadIdx.x;
  const int w = t >> 6, lane = t & 63, lm = lane & 15, q = lane >> 4;
  const int half = blockIdx.y & 1, bh = blockIdx.y >> 1, b = bh >> 4, h = bh & 15;
  const int u0 = blockIdx.x * 64;
  const int nrows = (Un - u0 < 64) ? (Un - u0) : 64;
  if (t < 64) {
    int qi = topi[(size_t)bh * Un + ((t < nrows) ? (u0 + t) : 0)];
    qxL[t] = qi;
    rmL[t] = row_max[(size_t)bh * Ln + qi];
  }
  __syncthreads();
#pragma unroll
  for (int c = 0; c < 2; ++c) {
    int f = (c * 256 + t) * 8; int row = f >> 6, col = f & 63;
    size_t go = ((size_t)b * Ln + qxL[row]) * Dn + h * DHn + col;
    *(uint4*)&sQP[row * QPS + col] = *(const uint4*)&Qh[go];
  }
  __syncthreads();
  f16x8 aq[4][2];
#pragma unroll
  for (int mi = 0; mi < 4; ++mi)
#pragma unroll
    for (int ks = 0; ks < 2; ++ks)
      aq[mi][ks] = *(const f16x8*)&sQP[(mi * 16 + lm) * QPS + ks * 32 + q * 8];
  f32x4 oacc[4] = {};
  float dacc[4][4] = {};

  const f16* kbase = Kh + (size_t)b * Ln * Dn + h * DHn;
  const f16* vbase = Vth + (size_t)bh * DHn * Ln;

  // prologue: stage tile 0 into buffer 0; drain aq reads + staging, sync
  {
    const int l0 = half * 1024;
#pragma unroll
    for (int c = 0; c < 2; ++c) {
      int f = (c * 256 + t) * 8; int row = f >> 6, c16 = (f >> 3) & 7;
      int sc = (c16 ^ (row & 7)) << 3;
      gl_lds16(kbase + (size_t)(l0 + row) * Dn + sc, &sK[0][f]);
      gl_lds16(vbase + (size_t)row * Ln + l0 + sc, &sV[0][f]);
    }
  }
  asm volatile("s_waitcnt vmcnt(0) lgkmcnt(0)" ::: "memory");
  __builtin_amdgcn_s_barrier();

  for (int kt = 0; kt < 16; ++kt) {
    const int cur = kt & 1;
    f16x8 kb[2];
#pragma unroll
    for (int ks = 0; ks < 2; ++ks) {
      int row = w * 16 + lm;
      kb[ks] = *(const f16x8*)&sK[cur][row * 64 + (((ks * 4 + q) ^ (row & 7)) << 3)];
    }
    if (kt < 15) {  // issue next tile into the other buffer; stays in flight
      const int ln0 = half * 1024 + (kt + 1) * 64;
#pragma unroll
      for (int c = 0; c < 2; ++c) {
        int f = (c * 256 + t) * 8; int row = f >> 6, c16 = (f >> 3) & 7;
        int sc = (c16 ^ (row & 7)) << 3;
        gl_lds16(kbase + (size_t)(ln0 + row) * Dn + sc, &sK[cur ^ 1][f]);
        gl_lds16(vbase + (size_t)row * Ln + ln0 + sc, &sV[cur ^ 1][f]);
      }
    }
#pragma unroll
    for (int mi = 0; mi < 4; ++mi) {
      f32x4 acc = {0.f, 0.f, 0.f, 0.f};
      __builtin_amdgcn_s_setprio(1);
      acc = MFMA(aq[mi][0], kb[0], acc);
      acc = MFMA(aq[mi][1], kb[1], acc);
      __builtin_amdgcn_s_setprio(0);
#pragma unroll
      for (int r = 0; r < 4; ++r) {
        int row = mi * 16 + q * 4 + r;
        float p = __expf(acc[r] * PSC - rmL[row]);
        dacc[mi][r] += p;
        sQP[row * QPS + w * 16 + lm] = (f16)(p * SPf);
      }
    }
    // P visible + all LDS reads of buf[cur] drained; vmcnt NOT drained (T4)
    asm volatile("s_waitcnt lgkmcnt(0)" ::: "memory");
    __builtin_amdgcn_s_barrier();
    f16x8 vb[2];
#pragma unroll
    for (int ks = 0; ks < 2; ++ks) {
      int row = w * 16 + lm;
      vb[ks] = *(const f16x8*)&sV[cur][row * 64 + (((ks * 4 + q) ^ (row & 7)) << 3)];
    }
#pragma unroll
    for (int mi = 0; mi < 4; ++mi) {
      f16x8 pf0 = *(const f16x8*)&sQP[(mi * 16 + lm) * QPS + 0 * 32 + q * 8];
      f16x8 pf1 = *(const f16x8*)&sQP[(mi * 16 + lm) * QPS + 1 * 32 + q * 8];
      __builtin_amdgcn_s_setprio(1);
      oacc[mi] = MFMA(pf0, vb[0], oacc[mi]);
      oacc[mi] = MFMA(pf1, vb[1], oacc[mi]);
      __builtin_amdgcn_s_setprio(0);
    }
    // next tile's staging landed on all waves before anyone reads it
    asm volatile("s_waitcnt vmcnt(0)" ::: "memory");
    __builtin_amdgcn_s_barrier();
  }
#pragma unroll
  for (int mi = 0; mi < 4; ++mi)
#pragma unroll
    for (int r = 0; r < 4; ++r) {
      float v = dacc[mi][r];
      v += __shfl_xor(v, 1); v += __shfl_xor(v, 2);
      v += __shfl_xor(v, 4); v += __shfl_xor(v, 8);
      if (lm == 0) dred[mi * 16 + q * 4 + r][w] = v;
    }
  __syncthreads();
  const size_t pbase = ((size_t)half * BHn + bh) * 1280 + u0;
  if (t < 64)
    pD[pbase + t] = dred[t][0] + dred[t][1] + dred[t][2] + dred[t][3];
#pragma unroll
  for (int mi = 0; mi < 4; ++mi)
#pragma unroll
    for (int r = 0; r < 4; ++r) {
      int row = mi * 16 + q * 4 + r;
      pO[(pbase + row) * 64 + w * 16 + lm] = oacc[mi][r];
    }
}

// ---------------- combine halves, normalize, scatter to AOh ----------------
__global__ __launch_bounds__(256) void attn_combine(
    const float* __restrict__ pO, const float* __restrict__ pD,
    const int* __restrict__ topi, f16* __restrict__ AOh) {
  const int t = threadIdx.x;
  const int u0 = blockIdx.x * 64, bh = blockIdx.y, b = bh >> 4, h = bh & 15;
  const int nrows = (Un - u0 < 64) ? (Un - u0) : 64;
  const int row = t >> 2, pg = t & 3;
  if (row >= nrows) return;
  int qi = topi[(size_t)bh * Un + u0 + row];
  size_t i0 = (size_t)bh * 1280 + u0 + row;
  size_t i1 = (size_t)BHn * 1280 + i0;
  float dinv = 1.0f / (pD[i0] + pD[i1]);
  const float* p0 = &pO[i0 * 64 + pg * 16];
  const float* p1 = &pO[i1 * 64 + pg * 16];
  f16 buf[16];
#pragma unroll
  for (int c = 0; c < 4; ++c) {
    float4 a = *(const float4*)&p0[c * 4];
    float4 bb = *(const float4*)&p1[c * 4];
    buf[c * 4 + 0] = (f16)((a.x + bb.x) * dinv);
    buf[c * 4 + 1] = (f16)((a.y + bb.y) * dinv);
    buf[c * 4 + 2] = (f16)((a.z + bb.z) * dinv);
    buf[c * 4 + 3] = (f16)((a.w + bb.w) * dinv);
  }
  f16* dst = &AOh[((size_t)b * Ln + qi) * Dn + h * DHn + pg * 16];
  *(uint4*)&dst[0] = *(uint4*)&buf[0];
  *(uint4*)&dst[8] = *(uint4*)&buf[8];
}

extern "C" void kernel_launch(void* const* d_in, const int* in_sizes, int n_in,
                              void* d_out, int out_size, void* d_ws, size_t ws_size,
                              hipStream_t stream) {
  (void)in_sizes; (void)n_in; (void)out_size; (void)ws_size;
  const float* x  = (const float*)d_in[0];
  const float* Wq = (const float*)d_in[1];
  const float* bq = (const float*)d_in[2];
  const float* Wk = (const float*)d_in[3];
  const float* bk = (const float*)d_in[4];
  const float* Wv = (const float*)d_in[5];
  const float* bv = (const float*)d_in[6];
  const float* Wo = (const float*)d_in[7];
  const float* bo = (const float*)d_in[8];
  float* out = (float*)d_out;

  uint8_t* p = (uint8_t*)d_ws;
  const size_t NE = (size_t)Bn * Ln * Dn;          // 4 Mi elements
  f16* xh = (f16*)p;  p += NE * 2;
  f16* xl = (f16*)p;  p += NE * 2;
  f16* Wt_h = (f16*)p; p += (size_t)4096 * Dn * 2;   // rows 0-3071: QKV cat; 3072-4095: Wo
  f16* Wt_l = (f16*)p; p += (size_t)4096 * Dn * 2;
  f16* Qbh = (f16*)p; p += NE * 2;
  f16* Qbl = (f16*)p; p += NE * 2;
  f16* Kbh = (f16*)p; p += NE * 2;
  f16* Kbl = (f16*)p; p += NE * 2;
  f16* Vh16 = (f16*)p; p += NE * 2;
  f16* Vth  = (f16*)p; p += NE * 2;
  float* rowmax = (float*)p; p += (size_t)BHn * Ln * 4;
  float* spars  = (float*)p; p += (size_t)BHn * Ln * 4;
  float* ksum   = (float*)p; p += (size_t)BHn * DHn * 4;
  int* topi     = (int*)p;   p += (size_t)BHn * Un * 4;
  int* wrow     = (int*)p;   p += (size_t)BHn * WIN * 4;
  float* pmaxf  = (float*)p; p += (size_t)BHn * WIN * 8 * 4;
  float* psum   = (float*)p; p += (size_t)BHn * WIN * 8 * 4;
  float* pD     = (float*)p; p += (size_t)2 * BHn * 1280 * 4;
  float* pO     = (float*)p; p += (size_t)2 * BHn * 1280 * 64 * 4;   // 21 MB
  f16* AOh = xh;   // alias: x split dead after QKV GEMM

  dim3 blk(256);
  hipLaunchKernelGGL(prep_fused, dim3(4096 + 1024), blk, 0, stream,
                     x, xh, xl, (int)(NE / 4), Wq, Wk, Wv, Wo, Wt_h, Wt_l);
  hipLaunchKernelGGL(gemm_qkv, dim3(24, 32), blk, 0, stream, xh, xl, Wt_h, Wt_l,
                     bq, bk, bv, Qbh, Qbl, Kbh, Kbl, Vh16, Dn);
  hipMemsetAsync(ksum, 0, (size_t)BHn * DHn * 4, stream);
  hipLaunchKernelGGL(vk_fused, dim3(1024 + 256), blk, 0, stream, Vh16, Vth, Kbh, ksum);
  hipLaunchKernelGGL(attn_stats_mfma, dim3(Ln / 128, BHn), blk, 0, stream,
                     Qbh, Kbh, ksum, rowmax, spars);
  hipLaunchKernelGGL(topk_sort, dim3(BHn), dim3(1024), 0, stream, spars, topi, wrow);
  hipLaunchKernelGGL(refine_part, dim3(8, BHn), blk, 0, stream,
                     Qbh, Qbl, Kbh, Kbl, wrow, pmaxf, psum);
  hipLaunchKernelGGL(topk_final, dim3(BHn), dim3(64), 0, stream, pmaxf, psum, wrow, topi);
  hipMemsetAsync(AOh, 0, NE * 2, stream);
  hipLaunchKernelGGL(attn_sel_part, dim3((Un + 63) / 64, 2 * BHn), blk, 0, stream,
                     Qbh, Kbh, Vth, topi, rowmax, pO, pD);
  hipLaunchKernelGGL(attn_combine, dim3((Un + 63) / 64, BHn), blk, 0, stream,
                     pO, pD, topi, AOh);
  hipLaunchKernelGGL(gemm_a1, dim3(512), blk, 0, stream, AOh,
                     Wt_h + (size_t)3072 * Dn, Wt_l + (size_t)3072 * Dn, bo,
                     ESC_OUT, out, Bn * Ln, Dn, Dn);
}